// Round 9
// baseline (242.042 us; speedup 1.0000x reference)
//
#include <hip/hip_runtime.h>
#include <math.h>

#define KNN  20
#define INFK 0xFFFFFFFFu

typedef _Float16 half8 __attribute__((ext_vector_type(8)));
typedef float    f32x4 __attribute__((ext_vector_type(4)));

// ---- dual interleaved DPP wave64 min (two independent chains for ILP) ------
#define DPP_MIN_STEP2(va, vb, ctrl, rm)                                        \
    {                                                                          \
        unsigned _ta = (unsigned)__builtin_amdgcn_update_dpp(                  \
            (int)(va), (int)(va), (ctrl), (rm), 0xf, false);                   \
        unsigned _tb = (unsigned)__builtin_amdgcn_update_dpp(                  \
            (int)(vb), (int)(vb), (ctrl), (rm), 0xf, false);                   \
        (va) = ((va) < _ta) ? (va) : _ta;                                      \
        (vb) = ((vb) < _tb) ? (vb) : _tb;                                      \
    }

__device__ __forceinline__ void wave_min2(unsigned va, unsigned vb,
                                          unsigned& r0, unsigned& r1) {
    DPP_MIN_STEP2(va, vb, 0x111, 0xf);   // row_shr:1
    DPP_MIN_STEP2(va, vb, 0x112, 0xf);   // row_shr:2
    DPP_MIN_STEP2(va, vb, 0x114, 0xf);   // row_shr:4
    DPP_MIN_STEP2(va, vb, 0x118, 0xf);   // row_shr:8
    DPP_MIN_STEP2(va, vb, 0x142, 0xa);   // row_bcast:15
    DPP_MIN_STEP2(va, vb, 0x143, 0xc);   // row_bcast:31
    r0 = (unsigned)__builtin_amdgcn_readlane((int)va, 63);
    r1 = (unsigned)__builtin_amdgcn_readlane((int)vb, 63);
}

#define CE(a, b)                                                               \
    { unsigned _lo = ((a) < (b)) ? (a) : (b);                                  \
      unsigned _hi = ((a) < (b)) ? (b) : (a); (a) = _lo; (b) = _hi; }

__device__ __forceinline__ void insert4(unsigned (&cd)[4], unsigned key) {
    #pragma unroll
    for (int i = 0; i < 4; ++i) CE(cd[i], key);
}

__device__ __forceinline__ void merge44(unsigned (&a)[4], unsigned (&b)[4],
                                        unsigned (&o)[8]) {
    CE(a[0], b[0]); CE(a[1], b[1]); CE(a[2], b[2]); CE(a[3], b[3]);
    CE(a[2], b[0]); CE(a[3], b[1]);
    CE(a[1], a[2]); CE(a[3], b[0]); CE(b[1], b[2]);
    o[0] = a[0]; o[1] = a[1]; o[2] = a[2]; o[3] = a[3];
    o[4] = b[0]; o[5] = b[1]; o[6] = b[2]; o[7] = b[3];
}

// dual 20-round merge; lane r ends with neighbor r of each row.
__device__ __forceinline__ void merge20x2(unsigned (&c0)[8], unsigned (&c1)[8],
                                          int t, int& nb0, int& nb1) {
    nb0 = 0; nb1 = 0;
    #pragma unroll
    for (int r = 0; r < KNN; ++r) {
        unsigned k0, k1;
        wave_min2(c0[0], c1[0], k0, k1);
        nb0 = (t == r) ? (int)(k0 & 511u) : nb0;
        nb1 = (t == r) ? (int)(k1 & 511u) : nb1;
        const bool w0 = (c0[0] == k0), w1 = (c1[0] == k1);
        #pragma unroll
        for (int i = 0; i < 7; ++i) {
            c0[i] = w0 ? c0[i + 1] : c0[i];
            c1[i] = w1 ? c1[i + 1] : c1[i];
        }
        c0[7] = w0 ? INFK : c0[7];
        c1[7] = w1 ? INFK : c1[7];
    }
}

// canonical 4-chain dot; ALL sq/dot use this -> m==n diagonal exactly 0
__device__ __forceinline__ float dot16(const float4& o0, const float4& o1,
                                       const float4& o2, const float4& o3,
                                       const float4& a0, const float4& a1,
                                       const float4& a2, const float4& a3) {
    float d0 = 0.f, d1 = 0.f, d2 = 0.f, d3 = 0.f;
    d0 = fmaf(o0.x, a0.x, d0); d0 = fmaf(o0.y, a0.y, d0); d0 = fmaf(o0.z, a0.z, d0); d0 = fmaf(o0.w, a0.w, d0);
    d1 = fmaf(o1.x, a1.x, d1); d1 = fmaf(o1.y, a1.y, d1); d1 = fmaf(o1.z, a1.z, d1); d1 = fmaf(o1.w, a1.w, d1);
    d2 = fmaf(o2.x, a2.x, d2); d2 = fmaf(o2.y, a2.y, d2); d2 = fmaf(o2.z, a2.z, d2); d2 = fmaf(o2.w, a2.w, d2);
    d3 = fmaf(o3.x, a3.x, d3); d3 = fmaf(o3.y, a3.y, d3); d3 = fmaf(o3.z, a3.z, d3); d3 = fmaf(o3.w, a3.w, d3);
    return (d0 + d1) + (d2 + d3);
}

// dual-row candidate scan: shared candidate loads, LDS norms, two key streams
__device__ __forceinline__ void scan2(const float* __restrict__ base,
                                      const float* __restrict__ ssq,
                                      float sq0, float sq1, int t,
                                      const float4& p00, const float4& p01,
                                      const float4& p02, const float4& p03,
                                      const float4& p10, const float4& p11,
                                      const float4& p12, const float4& p13,
                                      unsigned (&cd0)[8], unsigned (&cd1)[8]) {
    unsigned ca0[4], cb0[4], ca1[4], cb1[4];
    #pragma unroll
    for (int i = 0; i < 4; ++i) { ca0[i] = INFK; cb0[i] = INFK; ca1[i] = INFK; cb1[i] = INFK; }
    #pragma unroll
    for (int j = 0; j < 8; ++j) {
        const int m = j * 64 + t;
        const float4* p = (const float4*)(base + m * 16);
        const float4 a0 = p[0], a1 = p[1], a2 = p[2], a3 = p[3];
        const float sm = ssq[m];
        const float dA = dot16(p00, p01, p02, p03, a0, a1, a2, a3);
        const float dB = dot16(p10, p11, p12, p13, a0, a1, a2, a3);
        const float v0 = fmaxf(sq0 + sm - 2.f * dA, 0.f);  // exact 0 at m==n
        const float v1 = fmaxf(sq1 + sm - 2.f * dB, 0.f);
        const unsigned k0 = (__float_as_uint(v0) & 0xFFFFFE00u) | (unsigned)m;
        const unsigned k1 = (__float_as_uint(v1) & 0xFFFFFE00u) | (unsigned)m;
        if (j < 4) { insert4(ca0, k0); insert4(ca1, k1); }
        else       { insert4(cb0, k0); insert4(cb1, k1); }
    }
    merge44(ca0, cb0, cd0);
    merge44(ca1, cb1, cd1);
}

// ---------------------------------------------------------------------------
// Fused persistent kernel. 1024 blocks (64/batch), each wave owns 2 rows.
// __launch_bounds__(256,4) caps VGPR at 128 -> >=4 blocks/CU -> all 1024
// blocks co-resident, so the per-batch spin cannot deadlock; clock64 valve
// converts any logic error into a visible wrong answer instead of a hang.
// ---------------------------------------------------------------------------
__global__ __launch_bounds__(256, 4)
void fused_kernel(const float* __restrict__ x, const float* __restrict__ w_fm1,
                  const float* __restrict__ w_fm2, const float* __restrict__ w_mix1,
                  const float* __restrict__ w_mix2, const float* __restrict__ m_last,
                  const float* __restrict__ b_cls, const float* __restrict__ w_cls,
                  float* __restrict__ R, half8* __restrict__ Bf, f32x4* __restrict__ Mf,
                  unsigned* __restrict__ ctr, float* __restrict__ out) {
    __shared__ float ssq[512];           // phase1: x-norms; phase2: R-norms
    __shared__ union {
        struct { float wcs[630]; float smix2[1500]; } prep;   // phase1, first blk
        struct { float NRs[4][344]; } ph2;                    // phase2
    } u;
    __shared__ float pool8[8];
    const int tid   = threadIdx.x;
    const int bidx  = blockIdx.x;
    const int batch = bidx >> 6;         // 64 blocks per batch
    const int bb    = bidx & 63;
    const bool firstblk = (bb == 0);
    const float* xb = x + (size_t)batch * 8192;
    float*       Rb = R + (size_t)batch * 8192;

    // ---------------- phase 1 ----------------
    if (firstblk && tid < 40) out[batch * 40 + tid] = b_cls[tid];

    if (firstblk) {                      // per-batch fragment-table prep
        for (int e = tid; e < 1500; e += 256) u.prep.smix2[e] = w_mix2[e];
        if (tid < 30) {
            float wr[KNN]; float mx = -__builtin_inff();
            #pragma unroll
            for (int k = 0; k < KNN; ++k) { wr[k] = w_fm2[tid * KNN + k]; mx = fmaxf(mx, wr[k]); }
            float s = 0.f;
            #pragma unroll
            for (int k = 0; k < KNN; ++k) { wr[k] = __expf(wr[k] - mx); s += wr[k]; }
            const float scale = w_mix1[tid] / s;
            #pragma unroll
            for (int k = 0; k < KNN; ++k) u.prep.wcs[tid * 21 + k] = wr[k] * scale;
        }
    }

    for (int m = tid; m < 512; m += 256) {
        const float4* p = (const float4*)(xb + m * 16);
        const float4 a0 = p[0], a1 = p[1], a2 = p[2], a3 = p[3];
        ssq[m] = dot16(a0, a1, a2, a3, a0, a1, a2, a3);
    }
    __syncthreads();

    if (firstblk) {
        // B[k=(lane>>4)*8+j][f=tile*16+(lane&15)] (f16); M: C/D-layout m_last
        const int lane = tid & 63, tile = tid >> 6;
        const int q = lane >> 4, c = lane & 15;
        const int f = tile * 16 + c;
        half8 hb;
        #pragma unroll
        for (int j = 0; j < 8; ++j) {
            const int k = q * 8 + j;
            float val = 0.f;
            if (k < KNN && f < 50) {
                #pragma unroll
                for (int cc = 0; cc < 30; ++cc)
                    val = fmaf(u.prep.wcs[cc * 21 + k], u.prep.smix2[cc * 50 + f], val);
            }
            hb[j] = (_Float16)val;
        }
        Bf[batch * 256 + tile * 64 + lane] = hb;
        f32x4 mf;
        #pragma unroll
        for (int r = 0; r < 4; ++r)
            mf[r] = (f < 50) ? m_last[(q * 4 + r) * 50 + f] : 0.f;
        Mf[batch * 256 + tile * 64 + lane] = mf;
    }

    const int t = tid & 63, w = tid >> 6;
    const int n0 = bb * 8 + w * 2;       // this wave's two rows: n0, n0+1

    // lane-parallel softmax(w_fm1): lane t<20 holds swn[t]
    float mx = w_fm1[0];
    #pragma unroll
    for (int k = 1; k < KNN; ++k) mx = fmaxf(mx, w_fm1[k]);
    float ex = (t < KNN) ? __expf(w_fm1[t] - mx) : 0.f;
    float ssum = ex;
    #pragma unroll
    for (int off = 1; off <= 32; off <<= 1) ssum += __shfl_xor(ssum, off, 64);
    const float mysw = ex / ssum;

    {
        const float4* A4 = (const float4*)(xb + n0 * 16);
        const float4 p00 = A4[0], p01 = A4[1], p02 = A4[2], p03 = A4[3];
        const float4* B4 = (const float4*)(xb + (n0 + 1) * 16);
        const float4 p10 = B4[0], p11 = B4[1], p12 = B4[2], p13 = B4[3];

        unsigned cd0[8], cd1[8];
        scan2(xb, ssq, ssq[n0], ssq[n0 + 1], t,
              p00, p01, p02, p03, p10, p11, p12, p13, cd0, cd1);
        int nb0, nb1;
        merge20x2(cd0, cd1, t, nb0, nb1);

        // wFM per row: gather 20x16 into 5 regs/lane, weighted partials
        const int kq = t >> 4;
        #pragma unroll
        for (int r2 = 0; r2 < 2; ++r2) {
            const int nbv = r2 ? nb1 : nb0;
            float part = 0.f;
            #pragma unroll
            for (int j = 0; j < 5; ++j) {
                const int e = j * 64 + t;
                const int nb = __shfl(nbv, e >> 4, 64);
                const float xv = xb[nb * 16 + (e & 15)];
                const float swk = __shfl(mysw, j * 4 + kq, 64);
                part = fmaf(swk, xv, part);
            }
            part += __shfl_xor(part, 16, 64);
            part += __shfl_xor(part, 32, 64);
            if (t < 16) Rb[(n0 + r2) * 16 + t] = part;
        }
    }

    // ---------------- per-batch sync ----------------
    __syncthreads();
    unsigned* cb = ctr + batch * 16;
    if (tid == 0) {
        __threadfence();
        __hip_atomic_fetch_add(cb, 1u, __ATOMIC_RELEASE, __HIP_MEMORY_SCOPE_AGENT);
        long long t0 = clock64();
        while (__hip_atomic_load(cb, __ATOMIC_ACQUIRE, __HIP_MEMORY_SCOPE_AGENT) < 64u) {
            __builtin_amdgcn_s_sleep(4);
            if (clock64() - t0 > 200000000LL) break;   // safety valve
        }
        __threadfence();
    }
    __syncthreads();

    // ---------------- phase 2 ----------------
    for (int m = tid; m < 512; m += 256) {
        const float4* p = (const float4*)(Rb + m * 16);
        const float4 a0 = p[0], a1 = p[1], a2 = p[2], a3 = p[3];
        ssq[m] = dot16(a0, a1, a2, a3, a0, a1, a2, a3);
    }
    __syncthreads();

    int nb0, nb1;
    {
        const float4* A4 = (const float4*)(Rb + n0 * 16);
        const float4 p00 = A4[0], p01 = A4[1], p02 = A4[2], p03 = A4[3];
        const float4* B4 = (const float4*)(Rb + (n0 + 1) * 16);
        const float4 p10 = B4[0], p11 = B4[1], p12 = B4[2], p13 = B4[3];

        unsigned cd0[8], cd1[8];
        scan2(Rb, ssq, ssq[n0], ssq[n0 + 1], t,
              p00, p01, p02, p03, p10, p11, p12, p13, cd0, cd1);
        merge20x2(cd0, cd1, t, nb0, nb1);
    }

    const int q = t >> 4, c = t & 15;
    #pragma unroll
    for (int r2 = 0; r2 < 2; ++r2) {
        const int nbv = r2 ? nb1 : nb0;
        #pragma unroll
        for (int j = 0; j < 5; ++j) {
            const int e = j * 64 + t;
            const int nb = __shfl(nbv, e >> 4, 64);
            u.ph2.NRs[w][(e >> 4) * 17 + (e & 15)] = Rb[nb * 16 + (e & 15)];
        }
        half8 af;
        #pragma unroll
        for (int j = 0; j < 8; ++j) {
            const int k = q * 8 + j;
            af[j] = (k < KNN) ? (_Float16)u.ph2.NRs[w][k * 17 + c] : (_Float16)0.f;
        }
        float dsum = 0.f;
        #pragma unroll
        for (int tile = 0; tile < 4; ++tile) {
            const half8 bf = Bf[batch * 256 + tile * 64 + t];
            const f32x4 mf = Mf[batch * 256 + tile * 64 + t];
            f32x4 acc = {0.f, 0.f, 0.f, 0.f};
            acc = __builtin_amdgcn_mfma_f32_16x16x32_f16(af, bf, acc, 0, 0, 0);
            float a2 = 0.f;
            #pragma unroll
            for (int r = 0; r < 4; ++r) {
                const float diff = acc[r] - mf[r];
                a2 = fmaf(diff, diff, a2);
            }
            a2 += __shfl_xor(a2, 16, 64);
            a2 += __shfl_xor(a2, 32, 64);
            const int f = tile * 16 + c;
            dsum += (f < 50) ? sqrtf(a2 + 1e-8f) : 0.f;
        }
        #pragma unroll
        for (int off = 32; off >= 1; off >>= 1) dsum += __shfl_xor(dsum, off, 64);
        if (t == 0) pool8[w * 2 + r2] = dsum * (1.0f / 200.0f);
    }
    __syncthreads();

    if (tid < 40) {
        const int r0 = bb * 8;
        float a = 0.f;
        #pragma unroll
        for (int i = 0; i < 8; ++i)
            a = fmaf(pool8[i], w_cls[(r0 + i) * 40 + tid], a);
        unsafeAtomicAdd(&out[batch * 40 + tid], a);
    }
}

extern "C" void kernel_launch(void* const* d_in, const int* in_sizes, int n_in,
                              void* d_out, int out_size, void* d_ws, size_t ws_size,
                              hipStream_t stream) {
    const float* x      = (const float*)d_in[0];
    const float* w_fm1  = (const float*)d_in[1];
    const float* w_mix1 = (const float*)d_in[2];
    const float* w_fm2  = (const float*)d_in[3];
    const float* w_mix2 = (const float*)d_in[4];
    const float* m_last = (const float*)d_in[5];
    const float* w_cls  = (const float*)d_in[6];
    const float* b_cls  = (const float*)d_in[7];
    float* out = (float*)d_out;

    float*    ws  = (float*)d_ws;
    float*    R   = ws;                          // 131072 floats
    half8*    Bf  = (half8*)(ws + 131072);       // 16 x 256 x 16 B
    f32x4*    Mf  = (f32x4*)(ws + 147456);       // 16 x 256 x 16 B
    unsigned* ctr = (unsigned*)(ws + 163840);    // 16 counters, 64 B stride

    hipMemsetAsync(ctr, 0, 16 * 64, stream);
    fused_kernel<<<1024, 256, 0, stream>>>(x, w_fm1, w_fm2, w_mix1, w_mix2,
                                           m_last, b_cls, w_cls,
                                           R, Bf, Mf, ctr, out);
}

// Round 10
// 119.906 us; speedup vs baseline: 2.0186x; 2.0186x over previous
//
#include <hip/hip_runtime.h>
#include <math.h>

#define KNN  20
#define INFK 0xFFFFFFFFu

typedef _Float16 half8 __attribute__((ext_vector_type(8)));
typedef float    f32x4 __attribute__((ext_vector_type(4)));

// ---- paired (min, 2nd-min) DPP wave64 reduction ----------------------------
// old=INFK makes invalid/masked lanes combine as identity (required for the
// pair reduction; old=self would collapse s2 onto m). Consumed lanes (15/31/63)
// see disjoint windows, so (min,2nd) is exact.
#define DPP2_STEP(m, s, ctrl, rm)                                              \
    {                                                                          \
        unsigned _om = (unsigned)__builtin_amdgcn_update_dpp(                  \
            (int)0xFFFFFFFF, (int)(m), (ctrl), (rm), 0xf, false);              \
        unsigned _os = (unsigned)__builtin_amdgcn_update_dpp(                  \
            (int)0xFFFFFFFF, (int)(s), (ctrl), (rm), 0xf, false);              \
        const unsigned _hi = ((m) > _om) ? (m) : _om;                          \
        (m) = ((m) < _om) ? (m) : _om;                                         \
        const unsigned _s3 = ((s) < _os) ? (s) : _os;                          \
        (s) = (_s3 < _hi) ? _s3 : _hi;                                         \
    }

__device__ __forceinline__ void wave_min2_bcast(unsigned m, unsigned s,
                                                unsigned& k1, unsigned& k2) {
    DPP2_STEP(m, s, 0x111, 0xf);   // row_shr:1
    DPP2_STEP(m, s, 0x112, 0xf);   // row_shr:2
    DPP2_STEP(m, s, 0x114, 0xf);   // row_shr:4
    DPP2_STEP(m, s, 0x118, 0xf);   // row_shr:8
    DPP2_STEP(m, s, 0x142, 0xa);   // row_bcast:15
    DPP2_STEP(m, s, 0x143, 0xc);   // row_bcast:31
    k1 = (unsigned)__builtin_amdgcn_readlane((int)m, 63);
    k2 = (unsigned)__builtin_amdgcn_readlane((int)s, 63);
}

#define CE(a, b)                                                               \
    { unsigned _lo = ((a) < (b)) ? (a) : (b);                                  \
      unsigned _hi = ((a) < (b)) ? (b) : (a); (a) = _lo; (b) = _hi; }

__device__ __forceinline__ void insert4(unsigned (&cd)[4], unsigned key) {
    #pragma unroll
    for (int i = 0; i < 4; ++i) CE(cd[i], key);
}

__device__ __forceinline__ void merge44(unsigned (&a)[4], unsigned (&b)[4],
                                        unsigned (&o)[8]) {
    CE(a[0], b[0]); CE(a[1], b[1]); CE(a[2], b[2]); CE(a[3], b[3]);
    CE(a[2], b[0]); CE(a[3], b[1]);
    CE(a[1], a[2]); CE(a[3], b[0]); CE(b[1], b[2]);
    o[0] = a[0]; o[1] = a[1]; o[2] = a[2]; o[3] = a[3];
    o[4] = b[0]; o[5] = b[1]; o[6] = b[2]; o[7] = b[3];
}

// 10-round pair-extraction merge: round r yields ranks 2r (k1) and 2r+1 (k2),
// k1 < k2 (keys unique). Lane r ends holding neighbor index r in nbrv.
__device__ __forceinline__ int merge10x2(unsigned (&cd)[8], int t) {
    int nbrv = 0;
    #pragma unroll
    for (int r = 0; r < 10; ++r) {
        unsigned k1, k2;
        wave_min2_bcast(cd[0], cd[1], k1, k2);
        nbrv = (t == 2 * r)     ? (int)(k1 & 511u) : nbrv;
        nbrv = (t == 2 * r + 1) ? (int)(k2 & 511u) : nbrv;
        const bool w1  = (cd[0] == k1);
        const bool w2a = w1 && (cd[1] == k2);     // this lane owns both
        const bool sh1 = w1 || (cd[0] == k2);     // pop one
        #pragma unroll
        for (int i = 0; i < 7; ++i) cd[i] = sh1 ? cd[i + 1] : cd[i];
        cd[7] = sh1 ? INFK : cd[7];
        #pragma unroll
        for (int i = 0; i < 7; ++i) cd[i] = w2a ? cd[i + 1] : cd[i];
        cd[7] = w2a ? INFK : cd[7];
    }
    return nbrv;
}

// canonical 4-chain dot; ALL sq/dot use this -> m==n diagonal exactly 0
__device__ __forceinline__ float dot16(const float4& o0, const float4& o1,
                                       const float4& o2, const float4& o3,
                                       const float4& a0, const float4& a1,
                                       const float4& a2, const float4& a3) {
    float d0 = 0.f, d1 = 0.f, d2 = 0.f, d3 = 0.f;
    d0 = fmaf(o0.x, a0.x, d0); d0 = fmaf(o0.y, a0.y, d0); d0 = fmaf(o0.z, a0.z, d0); d0 = fmaf(o0.w, a0.w, d0);
    d1 = fmaf(o1.x, a1.x, d1); d1 = fmaf(o1.y, a1.y, d1); d1 = fmaf(o1.z, a1.z, d1); d1 = fmaf(o1.w, a1.w, d1);
    d2 = fmaf(o2.x, a2.x, d2); d2 = fmaf(o2.y, a2.y, d2); d2 = fmaf(o2.z, a2.z, d2); d2 = fmaf(o2.w, a2.w, d2);
    d3 = fmaf(o3.x, a3.x, d3); d3 = fmaf(o3.y, a3.y, d3); d3 = fmaf(o3.z, a3.z, d3); d3 = fmaf(o3.w, a3.w, d3);
    return (d0 + d1) + (d2 + d3);
}

// candidate scan: LDS norms, packed (dist,idx) keys, sorted-8 result
__device__ __forceinline__ void scan_candidates(const float* __restrict__ base,
                                                const float* __restrict__ ssq,
                                                float sqn, int t,
                                                const float4& o0, const float4& o1,
                                                const float4& o2, const float4& o3,
                                                unsigned (&cd)[8]) {
    unsigned ca[4], cb[4];
    #pragma unroll
    for (int i = 0; i < 4; ++i) { ca[i] = INFK; cb[i] = INFK; }
    #pragma unroll
    for (int j = 0; j < 8; ++j) {
        const int m = j * 64 + t;
        const float4* p = (const float4*)(base + m * 16);
        const float4 a0 = p[0], a1 = p[1], a2 = p[2], a3 = p[3];
        const float dot = dot16(o0, o1, o2, o3, a0, a1, a2, a3);
        float vd = fmaxf(sqn + ssq[m] - 2.f * dot, 0.f);   // exact 0 at m==n
        const unsigned key = (__float_as_uint(vd) & 0xFFFFFE00u) | (unsigned)m;
        if (j < 4) insert4(ca, key); else insert4(cb, key);
    }
    merge44(ca, cb, cd);
}

// ---------------------------------------------------------------------------
// Stage 1: KNN on raw points + wFM -> R. Block 0 builds the MFMA fragment
// tables (Q in f16, m_last in C/D layout); first block per batch writes bias.
// ---------------------------------------------------------------------------
__global__ __launch_bounds__(256)
void stage1_kernel(const float* __restrict__ x, const float* __restrict__ w_fm1,
                   const float* __restrict__ w_fm2, const float* __restrict__ w_mix1,
                   const float* __restrict__ w_mix2, const float* __restrict__ m_last,
                   const float* __restrict__ b_cls,
                   float* __restrict__ R,
                   half8* __restrict__ Bf, f32x4* __restrict__ Mf,
                   float* __restrict__ out) {
    __shared__ float ssq[512];
    __shared__ float swn[KNN];
    __shared__ float wcs[630];       // block 0 only
    __shared__ float smix2[1500];    // block 0 only
    const int tid   = threadIdx.x;
    const int bidx  = blockIdx.x;
    const int batch = bidx >> 7;     // 128 blocks per batch
    const float* xb = x + (size_t)batch * 8192;

    if ((bidx & 127) == 0 && tid < 40)
        out[batch * 40 + tid] = b_cls[tid];

    if (tid < KNN) {
        float v[KNN]; float mx = -__builtin_inff();
        #pragma unroll
        for (int k = 0; k < KNN; ++k) { v[k] = w_fm1[k]; mx = fmaxf(mx, v[k]); }
        float s = 0.f;
        #pragma unroll
        for (int k = 0; k < KNN; ++k) { v[k] = __expf(v[k] - mx); s += v[k]; }
        swn[tid] = v[tid] / s;
    }

    if (bidx == 0) {
        for (int e = tid; e < 1500; e += 256) smix2[e] = w_mix2[e];
        if (tid < 30) {
            float wr[KNN]; float mx = -__builtin_inff();
            #pragma unroll
            for (int k = 0; k < KNN; ++k) { wr[k] = w_fm2[tid * KNN + k]; mx = fmaxf(mx, wr[k]); }
            float s = 0.f;
            #pragma unroll
            for (int k = 0; k < KNN; ++k) { wr[k] = __expf(wr[k] - mx); s += wr[k]; }
            const float scale = w_mix1[tid] / s;
            #pragma unroll
            for (int k = 0; k < KNN; ++k) wcs[tid * 21 + k] = wr[k] * scale;
        }
    }

    for (int m = tid; m < 512; m += 256) {
        const float4* p = (const float4*)(xb + m * 16);
        const float4 a0 = p[0], a1 = p[1], a2 = p[2], a3 = p[3];
        ssq[m] = dot16(a0, a1, a2, a3, a0, a1, a2, a3);
    }
    __syncthreads();

    if (bidx == 0) {
        // B[k=(lane>>4)*8+j][f=tile*16+(lane&15)] (f16); M: C/D-layout m_last
        const int lane = tid & 63, tile = tid >> 6;
        const int q = lane >> 4, c = lane & 15;
        const int f = tile * 16 + c;
        half8 hb;
        #pragma unroll
        for (int j = 0; j < 8; ++j) {
            const int k = q * 8 + j;
            float val = 0.f;
            if (k < KNN && f < 50) {
                #pragma unroll
                for (int cc = 0; cc < 30; ++cc)
                    val = fmaf(wcs[cc * 21 + k], smix2[cc * 50 + f], val);
            }
            hb[j] = (_Float16)val;
        }
        Bf[tile * 64 + lane] = hb;
        f32x4 mf;
        #pragma unroll
        for (int r = 0; r < 4; ++r)
            mf[r] = (f < 50) ? m_last[(q * 4 + r) * 50 + f] : 0.f;
        Mf[tile * 64 + lane] = mf;
    }

    const int t = tid & 63, w = tid >> 6;
    const int row = bidx * 4 + w;
    const int n = row & 511;

    const float4* xn4 = (const float4*)(xb + n * 16);
    const float4 o0 = xn4[0], o1 = xn4[1], o2 = xn4[2], o3 = xn4[3];

    unsigned cd[8];
    scan_candidates(xb, ssq, ssq[n], t, o0, o1, o2, o3, cd);
    const int nbrv = merge10x2(cd, t);

    // gather: lane covers e = j*64+t -> (k = e>>4, d = e&15)
    float nrf[5];
    #pragma unroll
    for (int j = 0; j < 5; ++j) {
        const int e = j * 64 + t;
        const int nb = __shfl(nbrv, e >> 4, 64);
        nrf[j] = xb[nb * 16 + (e & 15)];
    }
    // partial wFM: lane t sums its 5 k's for d = t&15 (k = j*4 + (t>>4))
    const int kq = t >> 4;
    float part = 0.f;
    #pragma unroll
    for (int j = 0; j < 5; ++j) part = fmaf(swn[j * 4 + kq], nrf[j], part);
    part += __shfl_xor(part, 16, 64);
    part += __shfl_xor(part, 32, 64);
    if (t < 16) R[(size_t)row * 16 + t] = part;
}

// ---------------------------------------------------------------------------
// Stage 2: block-local R-norms (same dot16 chain -> diag exact 0), KNN on R,
// MFMA-fused wFM2.mix2 + manifold dist + pool + classifier atomics.
// ---------------------------------------------------------------------------
__global__ __launch_bounds__(256)
void stage2_kernel(const float* __restrict__ Rg,
                   const half8* __restrict__ Bfrag, const f32x4* __restrict__ Mfrag,
                   const float* __restrict__ w_cls, float* __restrict__ out) {
    __shared__ float ssq[512];
    __shared__ float NRs[4][344];    // [wave][20*17+pad] (stride 17 -> <=2-way)
    __shared__ float pool4[4];
    const int tid   = threadIdx.x;
    const int bidx  = blockIdx.x;
    const int batch = bidx >> 7;
    const float* Rb = Rg + (size_t)batch * 8192;

    for (int m = tid; m < 512; m += 256) {
        const float4* p = (const float4*)(Rb + m * 16);
        const float4 a0 = p[0], a1 = p[1], a2 = p[2], a3 = p[3];
        ssq[m] = dot16(a0, a1, a2, a3, a0, a1, a2, a3);
    }
    __syncthreads();

    const int t = tid & 63, w = tid >> 6;
    const int row = bidx * 4 + w;
    const int n = row & 511;

    const float4* rn4 = (const float4*)(Rb + n * 16);
    const float4 o0 = rn4[0], o1 = rn4[1], o2 = rn4[2], o3 = rn4[3];

    unsigned cd[8];
    scan_candidates(Rb, ssq, ssq[n], t, o0, o1, o2, o3, cd);
    const int nbrv = merge10x2(cd, t);

    // gather neighbor rows, bounce through padded LDS (wave-internal order)
    #pragma unroll
    for (int j = 0; j < 5; ++j) {
        const int e = j * 64 + t;
        const int nb = __shfl(nbrv, e >> 4, 64);
        NRs[w][(e >> 4) * 17 + (e & 15)] = Rb[nb * 16 + (e & 15)];
    }

    // A-fragment: A[m = t&15][k = (t>>4)*8+j] = NR[k][m], zero for k >= 20
    const int q = t >> 4, c = t & 15;
    half8 af;
    #pragma unroll
    for (int j = 0; j < 8; ++j) {
        const int k = q * 8 + j;
        af[j] = (k < KNN) ? (_Float16)NRs[w][k * 17 + c] : (_Float16)0.f;
    }

    float dsum = 0.f;
    #pragma unroll
    for (int tile = 0; tile < 4; ++tile) {
        const half8 bf = Bfrag[tile * 64 + t];
        const f32x4 mf = Mfrag[tile * 64 + t];
        f32x4 acc = {0.f, 0.f, 0.f, 0.f};
        acc = __builtin_amdgcn_mfma_f32_16x16x32_f16(af, bf, acc, 0, 0, 0);
        float a2 = 0.f;
        #pragma unroll
        for (int r = 0; r < 4; ++r) {
            const float diff = acc[r] - mf[r];
            a2 = fmaf(diff, diff, a2);
        }
        a2 += __shfl_xor(a2, 16, 64);
        a2 += __shfl_xor(a2, 32, 64);
        const int f = tile * 16 + c;
        dsum += (f < 50) ? sqrtf(a2 + 1e-8f) : 0.f;
    }
    // wave sum counts each f 4x (column replication) -> /4; pooled = /50
    #pragma unroll
    for (int off = 32; off >= 1; off >>= 1) dsum += __shfl_xor(dsum, off, 64);
    if (t == 0) pool4[w] = dsum * (1.0f / 200.0f);
    __syncthreads();

    if (tid < 40) {
        const int n0 = (bidx * 4) & 511;
        float a = 0.f;
        #pragma unroll
        for (int i = 0; i < 4; ++i)
            a = fmaf(pool4[i], w_cls[(n0 + i) * 40 + tid], a);
        unsafeAtomicAdd(&out[batch * 40 + tid], a);
    }
}

extern "C" void kernel_launch(void* const* d_in, const int* in_sizes, int n_in,
                              void* d_out, int out_size, void* d_ws, size_t ws_size,
                              hipStream_t stream) {
    const float* x      = (const float*)d_in[0];
    const float* w_fm1  = (const float*)d_in[1];
    const float* w_mix1 = (const float*)d_in[2];
    const float* w_fm2  = (const float*)d_in[3];
    const float* w_mix2 = (const float*)d_in[4];
    const float* m_last = (const float*)d_in[5];
    const float* w_cls  = (const float*)d_in[6];
    const float* b_cls  = (const float*)d_in[7];
    float* out = (float*)d_out;

    float* ws  = (float*)d_ws;
    float* R   = ws;                          // 131072 floats
    half8* Bf  = (half8*)(ws + 131072);       // 256 x 16 B
    f32x4* Mf  = (f32x4*)(ws + 132096);       // 256 x 16 B

    stage1_kernel<<<2048, 256, 0, stream>>>(x, w_fm1, w_fm2, w_mix1, w_mix2,
                                            m_last, b_cls, R, Bf, Mf, out);
    stage2_kernel<<<2048, 256, 0, stream>>>(R, Bf, Mf, w_cls, out);
}